// Round 1
// baseline (1393.488 us; speedup 1.0000x reference)
//
#include <hip/hip_runtime.h>
#include <math.h>

#define N_NODES  100000
#define N_EDGES  1600000
#define N_FEAT   128
#define N_HID    64
#define N_CLASS  10
#define N_GRAPHS 1000

// ---------------- pre: h = x @ pre_w + pre_b  (no relu) ----------------
// one wave per node; lane j caches column j of W in 128 VGPRs; x row is
// wave-uniform -> scalar-load broadcast (SMEM pipe, free vs VALU).
__global__ __launch_bounds__(256) void pre_kernel(
    const float* __restrict__ x, const float* __restrict__ W,
    const float* __restrict__ b, float* __restrict__ h)
{
    const int lane = threadIdx.x & 63;
    float w[N_FEAT];
#pragma unroll
    for (int k = 0; k < N_FEAT; ++k) w[k] = W[k * N_HID + lane];
    const float bj = b[lane];
    const int nw = gridDim.x * 4;
    for (int node = blockIdx.x * 4 + (threadIdx.x >> 6); node < N_NODES; node += nw) {
        const int un = __builtin_amdgcn_readfirstlane(node);
        const float* row = x + (size_t)un * N_FEAT;
        float acc = bj;
#pragma unroll
        for (int k = 0; k < N_FEAT; ++k) acc = fmaf(row[k], w[k], acc);
        h[(size_t)un * N_HID + lane] = acc;
    }
}

// ---------------- copy (agg = h), float4 vectorized ----------------
__global__ __launch_bounds__(256) void copy_kernel(
    const float* __restrict__ src, float* __restrict__ dst, int n4)
{
    const float4* s = (const float4*)src;
    float4* d = (float4*)dst;
    int stride = gridDim.x * blockDim.x;
    for (int i = blockIdx.x * blockDim.x + threadIdx.x; i < n4; i += stride)
        d[i] = s[i];
}

// ---------------- scatter: agg[dst] += h[src], one wave per edge ----------------
__global__ __launch_bounds__(256) void scatter_kernel(
    const float* __restrict__ h, float* __restrict__ agg,
    const int* __restrict__ ei)
{
    const int lane = threadIdx.x & 63;
    const int nw = gridDim.x * 4;
    for (int e = blockIdx.x * 4 + (threadIdx.x >> 6); e < N_EDGES; e += nw) {
        const int s = __builtin_amdgcn_readfirstlane(ei[e]);            // src (x_j)
        const int d = __builtin_amdgcn_readfirstlane(ei[N_EDGES + e]);  // dst
        const float v = h[(size_t)s * N_HID + lane];
        atomicAdd(&agg[(size_t)d * N_HID + lane], v);
    }
}

// ---------------- MLP: h = relu( relu(agg@W1+b1) @ W2 + b2 ) ----------------
// wave per node; W1/W2 columns in 128 VGPRs; first matvec input via scalar
// broadcast loads; z broadcast between matvecs via v_readlane (VALU, no LDS).
__global__ __launch_bounds__(256) void mlp_kernel(
    const float* __restrict__ in, float* __restrict__ out,
    const float* __restrict__ W1, const float* __restrict__ b1,
    const float* __restrict__ W2, const float* __restrict__ b2)
{
    const int lane = threadIdx.x & 63;
    float w1[N_HID], w2[N_HID];
#pragma unroll
    for (int k = 0; k < N_HID; ++k) w1[k] = W1[k * N_HID + lane];
#pragma unroll
    for (int k = 0; k < N_HID; ++k) w2[k] = W2[k * N_HID + lane];
    const float b1j = b1[lane];
    const float b2j = b2[lane];
    const int nw = gridDim.x * 4;
    for (int node = blockIdx.x * 4 + (threadIdx.x >> 6); node < N_NODES; node += nw) {
        const int un = __builtin_amdgcn_readfirstlane(node);
        const float* row = in + (size_t)un * N_HID;
        float acc = b1j;
#pragma unroll
        for (int k = 0; k < N_HID; ++k) acc = fmaf(row[k], w1[k], acc);
        const float z = fmaxf(acc, 0.0f);
        float acc2 = b2j;
#pragma unroll
        for (int k = 0; k < N_HID; ++k) {
            const float zk = __int_as_float(
                __builtin_amdgcn_readlane(__float_as_int(z), k));
            acc2 = fmaf(zk, w2[k], acc2);
        }
        out[(size_t)un * N_HID + lane] = fmaxf(acc2, 0.0f);
    }
}

// ---------------- pool: g[graph] = sum_{batch[i]==graph} h[i]  ----------------
// batch is sorted -> binary-search segment bounds; block per graph, no atomics.
__global__ __launch_bounds__(256) void pool_kernel(
    const float* __restrict__ h, const int* __restrict__ batch,
    float* __restrict__ g)
{
    const int graph = blockIdx.x;
    int l = 0, r = N_NODES;
    while (l < r) { int m = (l + r) >> 1; if (batch[m] < graph) l = m + 1; else r = m; }
    const int lo = l;
    r = N_NODES;
    while (l < r) { int m = (l + r) >> 1; if (batch[m] < graph + 1) l = m + 1; else r = m; }
    const int hi = l;

    const int lane = threadIdx.x & 63;
    const int wave = threadIdx.x >> 6;
    float acc = 0.0f;
    for (int i = lo + wave; i < hi; i += 4)
        acc += h[(size_t)i * N_HID + lane];
    __shared__ float sacc[4][N_HID];
    sacc[wave][lane] = acc;
    __syncthreads();
    if (wave == 0) {
        g[(size_t)graph * N_HID + lane] =
            sacc[0][lane] + sacc[1][lane] + sacc[2][lane] + sacc[3][lane];
    }
}

// ---------------- head: relu(g@post_w+post_b) @ ro_w + ro_b -> log_softmax ----
// one wave per graph (grid sized exactly: 250 blocks * 4 waves = 1000 graphs).
__global__ __launch_bounds__(256) void head_kernel(
    const float* __restrict__ g,
    const float* __restrict__ Wp, const float* __restrict__ bp,
    const float* __restrict__ Wr, const float* __restrict__ br,
    float* __restrict__ out)
{
    const int lane = threadIdx.x & 63;
    const int wave = threadIdx.x >> 6;
    const int graph = blockIdx.x * 4 + wave;

    float wp[N_HID];
#pragma unroll
    for (int k = 0; k < N_HID; ++k) wp[k] = Wp[k * N_HID + lane];

    const int un = __builtin_amdgcn_readfirstlane(graph);
    const float* row = g + (size_t)un * N_HID;
    float acc = bp[lane];
#pragma unroll
    for (int k = 0; k < N_HID; ++k) acc = fmaf(row[k], wp[k], acc);
    const float z = fmaxf(acc, 0.0f);

    float logit = (lane < N_CLASS) ? br[lane] : 0.0f;
#pragma unroll
    for (int k = 0; k < N_HID; ++k) {
        const float zk = __int_as_float(
            __builtin_amdgcn_readlane(__float_as_int(z), k));
        if (lane < N_CLASS)
            logit = fmaf(zk, Wr[k * N_CLASS + lane], logit);
    }

    __shared__ float slog[4][N_CLASS];
    if (lane < N_CLASS) slog[wave][lane] = logit;
    // same-wave LDS RAW: compiler inserts lgkmcnt wait; no cross-wave sharing.
    if (lane < N_CLASS) {
        float m = -INFINITY;
#pragma unroll
        for (int c = 0; c < N_CLASS; ++c) m = fmaxf(m, slog[wave][c]);
        float sum = 0.0f;
#pragma unroll
        for (int c = 0; c < N_CLASS; ++c) sum += expf(slog[wave][c] - m);
        out[(size_t)un * N_CLASS + lane] = logit - m - logf(sum);
    }
}

extern "C" void kernel_launch(void* const* d_in, const int* in_sizes, int n_in,
                              void* d_out, int out_size, void* d_ws, size_t ws_size,
                              hipStream_t stream)
{
    const float* x       = (const float*)d_in[0];
    const int*   ei      = (const int*)d_in[1];   // [2, E]: row0=src, row1=dst
    const int*   batch   = (const int*)d_in[2];
    const float* pre_w   = (const float*)d_in[3];
    const float* pre_b   = (const float*)d_in[4];
    const float* conv_w1 = (const float*)d_in[5]; // [3,64,64]
    const float* conv_b1 = (const float*)d_in[6]; // [3,64]
    const float* conv_w2 = (const float*)d_in[7];
    const float* conv_b2 = (const float*)d_in[8];
    const float* post_w  = (const float*)d_in[9];
    const float* post_b  = (const float*)d_in[10];
    const float* ro_w    = (const float*)d_in[11];
    const float* ro_b    = (const float*)d_in[12];
    float* out = (float*)d_out;

    float* h   = (float*)d_ws;                       // 100000*64 floats
    float* agg = h   + (size_t)N_NODES * N_HID;      // 100000*64 floats
    float* g   = agg + (size_t)N_NODES * N_HID;      // 1000*64 floats

    pre_kernel<<<1024, 256, 0, stream>>>(x, pre_w, pre_b, h);

    for (int l = 0; l < 3; ++l) {
        copy_kernel<<<2048, 256, 0, stream>>>(h, agg, N_NODES * N_HID / 4);
        scatter_kernel<<<8192, 256, 0, stream>>>(h, agg, ei);
        mlp_kernel<<<1024, 256, 0, stream>>>(
            agg, h,
            conv_w1 + (size_t)l * N_HID * N_HID, conv_b1 + (size_t)l * N_HID,
            conv_w2 + (size_t)l * N_HID * N_HID, conv_b2 + (size_t)l * N_HID);
    }

    pool_kernel<<<N_GRAPHS, 256, 0, stream>>>(h, batch, g);
    head_kernel<<<N_GRAPHS / 4, 256, 0, stream>>>(g, post_w, post_b, ro_w, ro_b, out);
}

// Round 2
// 754.152 us; speedup vs baseline: 1.8478x; 1.8478x over previous
//
#include <hip/hip_runtime.h>
#include <math.h>

#define N_NODES  100000
#define N_EDGES  1600000
#define N_FEAT   128
#define N_HID    64
#define N_CLASS  10
#define N_GRAPHS 1000
#define SCAN_NB  98   // ceil(100000/1024)

// ---------------- zero int array ----------------
__global__ __launch_bounds__(256) void zero_kernel(int* __restrict__ p, int n)
{
    int stride = gridDim.x * blockDim.x;
    for (int i = blockIdx.x * blockDim.x + threadIdx.x; i < n; i += stride)
        p[i] = 0;
}

// ---------------- degree histogram over dst ----------------
__global__ __launch_bounds__(256) void hist_kernel(
    const int* __restrict__ ei, int* __restrict__ deg)
{
    int stride = gridDim.x * blockDim.x;
    for (int e = blockIdx.x * blockDim.x + threadIdx.x; e < N_EDGES; e += stride)
        atomicAdd(&deg[ei[N_EDGES + e]], 1);
}

// ---------------- scan stage 1: per-block (1024 elems) exclusive scan ----------
__global__ __launch_bounds__(256) void scan1_kernel(
    const int* __restrict__ deg, int* __restrict__ pre, int* __restrict__ bsum)
{
    __shared__ int tsum[256];
    const int base = blockIdx.x * 1024 + threadIdx.x * 4;
    int v[4];
#pragma unroll
    for (int j = 0; j < 4; ++j)
        v[j] = (base + j < N_NODES) ? deg[base + j] : 0;
    int run = 0;
#pragma unroll
    for (int j = 0; j < 4; ++j) { int t = v[j]; v[j] = run; run += t; }
    tsum[threadIdx.x] = run;
    __syncthreads();
    // Hillis-Steele inclusive scan over 256 thread sums
    for (int off = 1; off < 256; off <<= 1) {
        int t = (threadIdx.x >= off) ? tsum[threadIdx.x - off] : 0;
        __syncthreads();
        tsum[threadIdx.x] += t;
        __syncthreads();
    }
    const int excl = (threadIdx.x > 0) ? tsum[threadIdx.x - 1] : 0;
#pragma unroll
    for (int j = 0; j < 4; ++j)
        if (base + j < N_NODES) pre[base + j] = v[j] + excl;
    if (threadIdx.x == 255) bsum[blockIdx.x] = tsum[255];
}

// ---------------- scan stage 2: serial scan of 98 block sums ----------------
__global__ void scan2_kernel(int* __restrict__ bsum)
{
    if (threadIdx.x == 0 && blockIdx.x == 0) {
        int run = 0;
        for (int i = 0; i < SCAN_NB; ++i) { int t = bsum[i]; bsum[i] = run; run += t; }
    }
}

// ---------------- scan stage 3: add block offset; init cursor ----------------
__global__ __launch_bounds__(256) void scan3_kernel(
    const int* __restrict__ pre, const int* __restrict__ bsum,
    int* __restrict__ row, int* __restrict__ cursor)
{
    int stride = gridDim.x * blockDim.x;
    for (int i = blockIdx.x * blockDim.x + threadIdx.x; i < N_NODES; i += stride) {
        int v = pre[i] + bsum[i >> 10];
        row[i] = v;
        cursor[i] = v;
    }
}

// ---------------- CSR fill: csr_src[pos] = src, grouped by dst ----------------
__global__ __launch_bounds__(256) void fill_kernel(
    const int* __restrict__ ei, int* __restrict__ cursor, int* __restrict__ csr)
{
    int stride = gridDim.x * blockDim.x;
    for (int e = blockIdx.x * blockDim.x + threadIdx.x; e < N_EDGES; e += stride) {
        int s = ei[e];
        int d = ei[N_EDGES + e];
        int p = atomicAdd(&cursor[d], 1);
        csr[p] = s;
    }
}

// ---------------- gather: agg[i] = h[i] + sum_{e in row[i]} h[csr[e]] ----------
// one wave per node; edge list is wave-uniform -> scalar indices; unroll 4 for MLP
__global__ __launch_bounds__(256) void gather_kernel(
    const float* __restrict__ h, float* __restrict__ agg,
    const int* __restrict__ csr, const int* __restrict__ row,
    const int* __restrict__ deg)
{
    const int lane = threadIdx.x & 63;
    const int nw = gridDim.x * 4;
    for (int node = blockIdx.x * 4 + (threadIdx.x >> 6); node < N_NODES; node += nw) {
        const int un = __builtin_amdgcn_readfirstlane(node);
        const int lo = __builtin_amdgcn_readfirstlane(row[un]);
        const int n  = __builtin_amdgcn_readfirstlane(deg[un]);
        const int hi = lo + n;
        float acc = h[(size_t)un * N_HID + lane];
        int e = lo;
        for (; e + 4 <= hi; e += 4) {
            const int s0 = __builtin_amdgcn_readfirstlane(csr[e]);
            const int s1 = __builtin_amdgcn_readfirstlane(csr[e + 1]);
            const int s2 = __builtin_amdgcn_readfirstlane(csr[e + 2]);
            const int s3 = __builtin_amdgcn_readfirstlane(csr[e + 3]);
            const float a0 = h[(size_t)s0 * N_HID + lane];
            const float a1 = h[(size_t)s1 * N_HID + lane];
            const float a2 = h[(size_t)s2 * N_HID + lane];
            const float a3 = h[(size_t)s3 * N_HID + lane];
            acc += (a0 + a1) + (a2 + a3);
        }
        for (; e < hi; ++e) {
            const int s = __builtin_amdgcn_readfirstlane(csr[e]);
            acc += h[(size_t)s * N_HID + lane];
        }
        agg[(size_t)un * N_HID + lane] = acc;
    }
}

// ---------------- pre: h = x @ pre_w + pre_b ----------------
__global__ __launch_bounds__(256) void pre_kernel(
    const float* __restrict__ x, const float* __restrict__ W,
    const float* __restrict__ b, float* __restrict__ h)
{
    const int lane = threadIdx.x & 63;
    float w[N_FEAT];
#pragma unroll
    for (int k = 0; k < N_FEAT; ++k) w[k] = W[k * N_HID + lane];
    const float bj = b[lane];
    const int nw = gridDim.x * 4;
    for (int node = blockIdx.x * 4 + (threadIdx.x >> 6); node < N_NODES; node += nw) {
        const int un = __builtin_amdgcn_readfirstlane(node);
        const float* row = x + (size_t)un * N_FEAT;
        float acc = bj;
#pragma unroll
        for (int k = 0; k < N_FEAT; ++k) acc = fmaf(row[k], w[k], acc);
        h[(size_t)un * N_HID + lane] = acc;
    }
}

// ---------------- MLP: h = relu( relu(agg@W1+b1) @ W2 + b2 ) ----------------
__global__ __launch_bounds__(256) void mlp_kernel(
    const float* __restrict__ in, float* __restrict__ out,
    const float* __restrict__ W1, const float* __restrict__ b1,
    const float* __restrict__ W2, const float* __restrict__ b2)
{
    const int lane = threadIdx.x & 63;
    float w1[N_HID], w2[N_HID];
#pragma unroll
    for (int k = 0; k < N_HID; ++k) w1[k] = W1[k * N_HID + lane];
#pragma unroll
    for (int k = 0; k < N_HID; ++k) w2[k] = W2[k * N_HID + lane];
    const float b1j = b1[lane];
    const float b2j = b2[lane];
    const int nw = gridDim.x * 4;
    for (int node = blockIdx.x * 4 + (threadIdx.x >> 6); node < N_NODES; node += nw) {
        const int un = __builtin_amdgcn_readfirstlane(node);
        const float* row = in + (size_t)un * N_HID;
        float acc = b1j;
#pragma unroll
        for (int k = 0; k < N_HID; ++k) acc = fmaf(row[k], w1[k], acc);
        const float z = fmaxf(acc, 0.0f);
        float acc2 = b2j;
#pragma unroll
        for (int k = 0; k < N_HID; ++k) {
            const float zk = __int_as_float(
                __builtin_amdgcn_readlane(__float_as_int(z), k));
            acc2 = fmaf(zk, w2[k], acc2);
        }
        out[(size_t)un * N_HID + lane] = fmaxf(acc2, 0.0f);
    }
}

// ---------------- pool: g[graph] = sum_{batch[i]==graph} h[i] ----------------
__global__ __launch_bounds__(256) void pool_kernel(
    const float* __restrict__ h, const int* __restrict__ batch,
    float* __restrict__ g)
{
    const int graph = blockIdx.x;
    int l = 0, r = N_NODES;
    while (l < r) { int m = (l + r) >> 1; if (batch[m] < graph) l = m + 1; else r = m; }
    const int lo = l;
    r = N_NODES;
    while (l < r) { int m = (l + r) >> 1; if (batch[m] < graph + 1) l = m + 1; else r = m; }
    const int hi = l;

    const int lane = threadIdx.x & 63;
    const int wave = threadIdx.x >> 6;
    float acc = 0.0f;
    for (int i = lo + wave; i < hi; i += 4)
        acc += h[(size_t)i * N_HID + lane];
    __shared__ float sacc[4][N_HID];
    sacc[wave][lane] = acc;
    __syncthreads();
    if (wave == 0) {
        g[(size_t)graph * N_HID + lane] =
            sacc[0][lane] + sacc[1][lane] + sacc[2][lane] + sacc[3][lane];
    }
}

// ---------------- head: relu(g@post_w+post_b) @ ro_w + ro_b -> log_softmax ----
__global__ __launch_bounds__(256) void head_kernel(
    const float* __restrict__ g,
    const float* __restrict__ Wp, const float* __restrict__ bp,
    const float* __restrict__ Wr, const float* __restrict__ br,
    float* __restrict__ out)
{
    const int lane = threadIdx.x & 63;
    const int wave = threadIdx.x >> 6;
    const int graph = blockIdx.x * 4 + wave;

    float wp[N_HID];
#pragma unroll
    for (int k = 0; k < N_HID; ++k) wp[k] = Wp[k * N_HID + lane];

    const int un = __builtin_amdgcn_readfirstlane(graph);
    const float* row = g + (size_t)un * N_HID;
    float acc = bp[lane];
#pragma unroll
    for (int k = 0; k < N_HID; ++k) acc = fmaf(row[k], wp[k], acc);
    const float z = fmaxf(acc, 0.0f);

    float logit = (lane < N_CLASS) ? br[lane] : 0.0f;
#pragma unroll
    for (int k = 0; k < N_HID; ++k) {
        const float zk = __int_as_float(
            __builtin_amdgcn_readlane(__float_as_int(z), k));
        if (lane < N_CLASS)
            logit = fmaf(zk, Wr[k * N_CLASS + lane], logit);
    }

    __shared__ float slog[4][N_CLASS];
    if (lane < N_CLASS) slog[wave][lane] = logit;
    if (lane < N_CLASS) {
        float m = -INFINITY;
#pragma unroll
        for (int c = 0; c < N_CLASS; ++c) m = fmaxf(m, slog[wave][c]);
        float sum = 0.0f;
#pragma unroll
        for (int c = 0; c < N_CLASS; ++c) sum += expf(slog[wave][c] - m);
        out[(size_t)un * N_CLASS + lane] = logit - m - logf(sum);
    }
}

extern "C" void kernel_launch(void* const* d_in, const int* in_sizes, int n_in,
                              void* d_out, int out_size, void* d_ws, size_t ws_size,
                              hipStream_t stream)
{
    const float* x       = (const float*)d_in[0];
    const int*   ei      = (const int*)d_in[1];   // [2, E]: row0=src, row1=dst
    const int*   batch   = (const int*)d_in[2];
    const float* pre_w   = (const float*)d_in[3];
    const float* pre_b   = (const float*)d_in[4];
    const float* conv_w1 = (const float*)d_in[5];
    const float* conv_b1 = (const float*)d_in[6];
    const float* conv_w2 = (const float*)d_in[7];
    const float* conv_b2 = (const float*)d_in[8];
    const float* post_w  = (const float*)d_in[9];
    const float* post_b  = (const float*)d_in[10];
    const float* ro_w    = (const float*)d_in[11];
    const float* ro_b    = (const float*)d_in[12];
    float* out = (float*)d_out;

    // workspace layout
    float* h      = (float*)d_ws;                          // 6.4M f
    float* agg    = h + (size_t)N_NODES * N_HID;           // 6.4M f
    float* g      = agg + (size_t)N_NODES * N_HID;         // 64K f
    int*   deg    = (int*)(g + (size_t)N_GRAPHS * N_HID);  // 100K i
    int*   row    = deg + N_NODES;                         // 100K i
    int*   cursor = row + N_NODES;                         // 100K i
    int*   pre    = cursor + N_NODES;                      // 100K i (scan temp)
    int*   bsum   = pre + N_NODES;                         // 128 i
    int*   csr    = bsum + 128;                            // 1.6M i

    // ---- CSR build (once; reused by all 3 layers) ----
    zero_kernel<<<128, 256, 0, stream>>>(deg, N_NODES);
    hist_kernel<<<2048, 256, 0, stream>>>(ei, deg);
    scan1_kernel<<<SCAN_NB, 256, 0, stream>>>(deg, pre, bsum);
    scan2_kernel<<<1, 64, 0, stream>>>(bsum);
    scan3_kernel<<<128, 256, 0, stream>>>(pre, bsum, row, cursor);
    fill_kernel<<<2048, 256, 0, stream>>>(ei, cursor, csr);

    // ---- network ----
    pre_kernel<<<1024, 256, 0, stream>>>(x, pre_w, pre_b, h);

    for (int l = 0; l < 3; ++l) {
        gather_kernel<<<6144, 256, 0, stream>>>(h, agg, csr, row, deg);
        mlp_kernel<<<1024, 256, 0, stream>>>(
            agg, h,
            conv_w1 + (size_t)l * N_HID * N_HID, conv_b1 + (size_t)l * N_HID,
            conv_w2 + (size_t)l * N_HID * N_HID, conv_b2 + (size_t)l * N_HID);
    }

    pool_kernel<<<N_GRAPHS, 256, 0, stream>>>(h, batch, g);
    head_kernel<<<N_GRAPHS / 4, 256, 0, stream>>>(g, post_w, post_b, ro_w, ro_b, out);
}

// Round 4
// 641.268 us; speedup vs baseline: 2.1730x; 1.1760x over previous
//
#include <hip/hip_runtime.h>
#include <math.h>

#define N_NODES  100000
#define N_EDGES  1600000
#define N_FEAT   128
#define N_HID    64
#define N_CLASS  10
#define N_GRAPHS 1000
#define SCAN_NB  98        // ceil(100000/1024)
#define NPASS    6
#define PRANGE   16667     // ceil(100000/6)

// ---------------- zero int array ----------------
__global__ __launch_bounds__(256) void zero_kernel(int* __restrict__ p, int n)
{
    int stride = gridDim.x * blockDim.x;
    for (int i = blockIdx.x * blockDim.x + threadIdx.x; i < n; i += stride)
        p[i] = 0;
}

// ---- degree histogram over dst; atomic return value IS the edge's rank ----
__global__ __launch_bounds__(256) void hist_kernel(
    const int* __restrict__ ei, int* __restrict__ deg, int* __restrict__ rank)
{
    int stride = gridDim.x * blockDim.x;
    for (int e = blockIdx.x * blockDim.x + threadIdx.x; e < N_EDGES; e += stride)
        rank[e] = atomicAdd(&deg[ei[N_EDGES + e]], 1);
}

// ---------------- scan stage 1: per-block (1024 elems) exclusive scan ----------
__global__ __launch_bounds__(256) void scan1_kernel(
    const int* __restrict__ deg, int* __restrict__ pre, int* __restrict__ bsum)
{
    __shared__ int tsum[256];
    const int base = blockIdx.x * 1024 + threadIdx.x * 4;
    int v[4];
#pragma unroll
    for (int j = 0; j < 4; ++j)
        v[j] = (base + j < N_NODES) ? deg[base + j] : 0;
    int run = 0;
#pragma unroll
    for (int j = 0; j < 4; ++j) { int t = v[j]; v[j] = run; run += t; }
    tsum[threadIdx.x] = run;
    __syncthreads();
    for (int off = 1; off < 256; off <<= 1) {
        int t = (threadIdx.x >= off) ? tsum[threadIdx.x - off] : 0;
        __syncthreads();
        tsum[threadIdx.x] += t;
        __syncthreads();
    }
    const int excl = (threadIdx.x > 0) ? tsum[threadIdx.x - 1] : 0;
#pragma unroll
    for (int j = 0; j < 4; ++j)
        if (base + j < N_NODES) pre[base + j] = v[j] + excl;
    if (threadIdx.x == 255) bsum[blockIdx.x] = tsum[255];
}

// ---------------- scan stage 2: serial scan of 98 block sums ----------------
__global__ void scan2_kernel(int* __restrict__ bsum)
{
    if (threadIdx.x == 0 && blockIdx.x == 0) {
        int run = 0;
        for (int i = 0; i < SCAN_NB; ++i) { int t = bsum[i]; bsum[i] = run; run += t; }
    }
}

// ---------------- scan stage 3: add block offset -> row ptr ----------------
__global__ __launch_bounds__(256) void scan3_kernel(
    const int* __restrict__ pre, const int* __restrict__ bsum,
    int* __restrict__ row)
{
    int stride = gridDim.x * blockDim.x;
    for (int i = blockIdx.x * blockDim.x + threadIdx.x; i < N_NODES; i += stride)
        row[i] = pre[i] + bsum[i >> 10];
}

// ---- CSR fill: no atomics (pos = row[d]+rank[e]); 6 dst-range passes so the
// ---- active csr/row window (~1.1 MB / 67 KB) stays L2-resident ----
__global__ __launch_bounds__(256) void fill_kernel(
    const int* __restrict__ ei, const int* __restrict__ rank,
    const int* __restrict__ row, int* __restrict__ csr)
{
    const int stride = gridDim.x * blockDim.x;
    const int tid0 = blockIdx.x * blockDim.x + threadIdx.x;
    for (int pass = 0; pass < NPASS; ++pass) {
        const int lo = pass * PRANGE;
        const int hi = lo + PRANGE;
        for (int e = tid0; e < N_EDGES; e += stride) {
            const int d = ei[N_EDGES + e];
            if (d >= lo && d < hi)
                csr[row[d] + rank[e]] = ei[e];
        }
    }
}

// ---- gather: agg[i] = h[i] + sum_{e in row[i]} h[csr[e]] ----
// one wave per node. Bucket edge list fetched in ONE coalesced load (lane e ->
// csr[lo+e]); 16-lane groups each load a full 64-float row as float4/lane.
// CRITICAL: the edge loop bound `n` is an SGPR (wave-uniform), so ALL 64 lanes
// execute every iteration and every __shfl source lane is ACTIVE. ds_bpermute
// from an inactive lane is undefined on CDNA — a per-lane trip count here
// (round 3) silently corrupted nodes with deg==24 etc. Only the dependent
// loads are predicated (divergence around plain loads is safe).
__global__ __launch_bounds__(256) void gather_kernel(
    const float* __restrict__ h, float* __restrict__ agg,
    const int* __restrict__ csr, const int* __restrict__ row,
    const int* __restrict__ deg)
{
    const int lane = threadIdx.x & 63;
    const int grp  = lane >> 4;       // 0..3
    const int sub  = lane & 15;       // 0..15
    const int nw = gridDim.x * 4;
    for (int node = blockIdx.x * 4 + (threadIdx.x >> 6); node < N_NODES; node += nw) {
        const int un = __builtin_amdgcn_readfirstlane(node);
        const int lo = __builtin_amdgcn_readfirstlane(row[un]);
        const int n  = __builtin_amdgcn_readfirstlane(deg[un]);
        int eidx = 0;
        if (lane < n) eidx = csr[lo + lane];    // whole bucket, one load
        float ax = 0.f, ay = 0.f, az = 0.f, aw = 0.f;
        // self term: group 0 only (no shuffle inside — divergence is safe)
        if (grp == 0) {
            const float4 a = *(const float4*)(h + (size_t)un * N_HID + (sub << 2));
            ax += a.x; ay += a.y; az += a.z; aw += a.w;
        }
        for (int eb = 0; eb < n; eb += 8) {     // UNIFORM trip count
            const int j0 = eb + grp;
            const int j1 = j0 + 4;
            const int s0 = __shfl(eidx, j0, 64);  // full-EXEC shuffles
            const int s1 = __shfl(eidx, j1, 64);
            if (j0 < n) {
                const float4 a = *(const float4*)(h + (size_t)s0 * N_HID + (sub << 2));
                ax += a.x; ay += a.y; az += a.z; aw += a.w;
            }
            if (j1 < n) {
                const float4 a = *(const float4*)(h + (size_t)s1 * N_HID + (sub << 2));
                ax += a.x; ay += a.y; az += a.z; aw += a.w;
            }
        }
        // reduce across the 4 groups (all lanes active here)
        ax += __shfl_xor(ax, 16, 64); ay += __shfl_xor(ay, 16, 64);
        az += __shfl_xor(az, 16, 64); aw += __shfl_xor(aw, 16, 64);
        ax += __shfl_xor(ax, 32, 64); ay += __shfl_xor(ay, 32, 64);
        az += __shfl_xor(az, 32, 64); aw += __shfl_xor(aw, 32, 64);
        if (grp == 0) {
            float4 r = make_float4(ax, ay, az, aw);
            *(float4*)(agg + (size_t)un * N_HID + (sub << 2)) = r;
        }
    }
}

// ---------------- pre: h = x @ pre_w + pre_b ----------------
__global__ __launch_bounds__(256) void pre_kernel(
    const float* __restrict__ x, const float* __restrict__ W,
    const float* __restrict__ b, float* __restrict__ h)
{
    const int lane = threadIdx.x & 63;
    float w[N_FEAT];
#pragma unroll
    for (int k = 0; k < N_FEAT; ++k) w[k] = W[k * N_HID + lane];
    const float bj = b[lane];
    const int nw = gridDim.x * 4;
    for (int node = blockIdx.x * 4 + (threadIdx.x >> 6); node < N_NODES; node += nw) {
        const int un = __builtin_amdgcn_readfirstlane(node);
        const float* row = x + (size_t)un * N_FEAT;
        float acc = bj;
#pragma unroll
        for (int k = 0; k < N_FEAT; ++k) acc = fmaf(row[k], w[k], acc);
        h[(size_t)un * N_HID + lane] = acc;
    }
}

// ---------------- MLP: h = relu( relu(agg@W1+b1) @ W2 + b2 ) ----------------
__global__ __launch_bounds__(256) void mlp_kernel(
    const float* __restrict__ in, float* __restrict__ out,
    const float* __restrict__ W1, const float* __restrict__ b1,
    const float* __restrict__ W2, const float* __restrict__ b2)
{
    const int lane = threadIdx.x & 63;
    float w1[N_HID], w2[N_HID];
#pragma unroll
    for (int k = 0; k < N_HID; ++k) w1[k] = W1[k * N_HID + lane];
#pragma unroll
    for (int k = 0; k < N_HID; ++k) w2[k] = W2[k * N_HID + lane];
    const float b1j = b1[lane];
    const float b2j = b2[lane];
    const int nw = gridDim.x * 4;
    for (int node = blockIdx.x * 4 + (threadIdx.x >> 6); node < N_NODES; node += nw) {
        const int un = __builtin_amdgcn_readfirstlane(node);
        const float* row = in + (size_t)un * N_HID;
        float acc = b1j;
#pragma unroll
        for (int k = 0; k < N_HID; ++k) acc = fmaf(row[k], w1[k], acc);
        const float z = fmaxf(acc, 0.0f);
        float acc2 = b2j;
#pragma unroll
        for (int k = 0; k < N_HID; ++k) {
            const float zk = __int_as_float(
                __builtin_amdgcn_readlane(__float_as_int(z), k));  // exec-ignoring
            acc2 = fmaf(zk, w2[k], acc2);
        }
        out[(size_t)un * N_HID + lane] = fmaxf(acc2, 0.0f);
    }
}

// ---------------- pool: g[graph] = sum_{batch[i]==graph} h[i] ----------------
__global__ __launch_bounds__(256) void pool_kernel(
    const float* __restrict__ h, const int* __restrict__ batch,
    float* __restrict__ g)
{
    const int graph = blockIdx.x;
    int l = 0, r = N_NODES;
    while (l < r) { int m = (l + r) >> 1; if (batch[m] < graph) l = m + 1; else r = m; }
    const int lo = l;
    r = N_NODES;
    while (l < r) { int m = (l + r) >> 1; if (batch[m] < graph + 1) l = m + 1; else r = m; }
    const int hi = l;

    const int lane = threadIdx.x & 63;
    const int wave = threadIdx.x >> 6;
    float acc = 0.0f;
    for (int i = lo + wave; i < hi; i += 4)
        acc += h[(size_t)i * N_HID + lane];
    __shared__ float sacc[4][N_HID];
    sacc[wave][lane] = acc;
    __syncthreads();
    if (wave == 0) {
        g[(size_t)graph * N_HID + lane] =
            sacc[0][lane] + sacc[1][lane] + sacc[2][lane] + sacc[3][lane];
    }
}

// ---------------- head: relu(g@post_w+post_b) @ ro_w + ro_b -> log_softmax ----
__global__ __launch_bounds__(256) void head_kernel(
    const float* __restrict__ g,
    const float* __restrict__ Wp, const float* __restrict__ bp,
    const float* __restrict__ Wr, const float* __restrict__ br,
    float* __restrict__ out)
{
    const int lane = threadIdx.x & 63;
    const int wave = threadIdx.x >> 6;
    const int graph = blockIdx.x * 4 + wave;

    float wp[N_HID];
#pragma unroll
    for (int k = 0; k < N_HID; ++k) wp[k] = Wp[k * N_HID + lane];

    const int un = __builtin_amdgcn_readfirstlane(graph);
    const float* row = g + (size_t)un * N_HID;
    float acc = bp[lane];
#pragma unroll
    for (int k = 0; k < N_HID; ++k) acc = fmaf(row[k], wp[k], acc);
    const float z = fmaxf(acc, 0.0f);

    float logit = (lane < N_CLASS) ? br[lane] : 0.0f;
#pragma unroll
    for (int k = 0; k < N_HID; ++k) {
        const float zk = __int_as_float(
            __builtin_amdgcn_readlane(__float_as_int(z), k));  // exec-ignoring
        if (lane < N_CLASS)
            logit = fmaf(zk, Wr[k * N_CLASS + lane], logit);
    }

    __shared__ float slog[4][N_CLASS];
    if (lane < N_CLASS) slog[wave][lane] = logit;
    if (lane < N_CLASS) {
        float m = -INFINITY;
#pragma unroll
        for (int c = 0; c < N_CLASS; ++c) m = fmaxf(m, slog[wave][c]);
        float sum = 0.0f;
#pragma unroll
        for (int c = 0; c < N_CLASS; ++c) sum += expf(slog[wave][c] - m);
        out[(size_t)un * N_CLASS + lane] = logit - m - logf(sum);
    }
}

extern "C" void kernel_launch(void* const* d_in, const int* in_sizes, int n_in,
                              void* d_out, int out_size, void* d_ws, size_t ws_size,
                              hipStream_t stream)
{
    const float* x       = (const float*)d_in[0];
    const int*   ei      = (const int*)d_in[1];   // [2, E]: row0=src, row1=dst
    const int*   batch   = (const int*)d_in[2];
    const float* pre_w   = (const float*)d_in[3];
    const float* pre_b   = (const float*)d_in[4];
    const float* conv_w1 = (const float*)d_in[5];
    const float* conv_b1 = (const float*)d_in[6];
    const float* conv_w2 = (const float*)d_in[7];
    const float* conv_b2 = (const float*)d_in[8];
    const float* post_w  = (const float*)d_in[9];
    const float* post_b  = (const float*)d_in[10];
    const float* ro_w    = (const float*)d_in[11];
    const float* ro_b    = (const float*)d_in[12];
    float* out = (float*)d_out;

    // workspace layout (~59 MB)
    float* h      = (float*)d_ws;                          // 6.4M f
    float* agg    = h + (size_t)N_NODES * N_HID;           // 6.4M f
    float* g      = agg + (size_t)N_NODES * N_HID;         // 64K f
    int*   deg    = (int*)(g + (size_t)N_GRAPHS * N_HID);  // 100K i
    int*   row    = deg + N_NODES;                         // 100K i
    int*   pre    = row + N_NODES;                         // 100K i (scan temp)
    int*   bsum   = pre + N_NODES;                         // 128 i
    int*   csr    = bsum + 128;                            // 1.6M i
    int*   rank   = (int*)agg;   // alias: rank dead before gather writes agg

    // ---- CSR build (once; reused by all 3 layers) ----
    zero_kernel<<<128, 256, 0, stream>>>(deg, N_NODES);
    hist_kernel<<<2048, 256, 0, stream>>>(ei, deg, rank);
    scan1_kernel<<<SCAN_NB, 256, 0, stream>>>(deg, pre, bsum);
    scan2_kernel<<<1, 64, 0, stream>>>(bsum);
    scan3_kernel<<<128, 256, 0, stream>>>(pre, bsum, row);
    fill_kernel<<<2048, 256, 0, stream>>>(ei, rank, row, csr);

    // ---- network ----
    pre_kernel<<<1024, 256, 0, stream>>>(x, pre_w, pre_b, h);

    for (int l = 0; l < 3; ++l) {
        gather_kernel<<<6144, 256, 0, stream>>>(h, agg, csr, row, deg);
        mlp_kernel<<<1024, 256, 0, stream>>>(
            agg, h,
            conv_w1 + (size_t)l * N_HID * N_HID, conv_b1 + (size_t)l * N_HID,
            conv_w2 + (size_t)l * N_HID * N_HID, conv_b2 + (size_t)l * N_HID);
    }

    pool_kernel<<<N_GRAPHS, 256, 0, stream>>>(h, batch, g);
    head_kernel<<<N_GRAPHS / 4, 256, 0, stream>>>(g, post_w, post_b, ro_w, ro_b, out);
}